// Round 2
// baseline (990.597 us; speedup 1.0000x reference)
//
#include <hip/hip_runtime.h>

#define CIN 32
#define COUT 64
#define ID0 200
#define ID1 200
#define ID2 16
#define OD0 100
#define OD1 100
#define OD2 8
#define NVOX (2 * ID0 * ID1 * ID2)   // 1,280,000 (batch=2)
#define NC 16                        // output cells per wave

// ---------- rank selection: two-level 16-bit radix histograms ----------

// also builds the voxel->point chain (independent work, saves a launch)
__global__ void prep_kernel(const float* __restrict__ mask, const int* __restrict__ coors,
                            int n, int* __restrict__ hist,
                            int* __restrict__ head, int* __restrict__ nxt) {
    int i = blockIdx.x * blockDim.x + threadIdx.x;
    if (i >= n) return;
    unsigned bits = __float_as_uint(mask[i]);   // mask in [0,1): uint order == float order
    atomicAdd(&hist[bits >> 16], 1);
    int4 c = ((const int4*)coors)[i];
    int v = ((c.x * ID0 + c.y) * ID1 + c.z) * ID2 + c.w;
    nxt[i] = atomicExch(&head[v], i);
}

__global__ void hist_lo_kernel(const float* __restrict__ mask, int n,
                               const int* __restrict__ sel, int* __restrict__ hist) {
    int i = blockIdx.x * blockDim.x + threadIdx.x;
    if (i >= n) return;
    unsigned bits = __float_as_uint(mask[i]);
    if ((int)(bits >> 16) == sel[0]) atomicAdd(&hist[bits & 0xFFFFu], 1);
}

// One block, 256 threads. Finds bucket containing `rank` and residual rank.
__global__ void select_kernel(const int* __restrict__ hist, const int* rankSrc,
                              int rankConst, int* outPair) {
    __shared__ int partial[256];
    __shared__ int scan[257];
    int t = threadIdx.x;
    int rank = rankSrc ? *rankSrc : rankConst;
    const int* h = hist + t * 256;
    int sum = 0;
    for (int j = 0; j < 256; j++) sum += h[j];
    partial[t] = sum;
    __syncthreads();
    if (t == 0) {
        int c = 0;
        for (int j = 0; j < 256; j++) { scan[j] = c; c += partial[j]; }
        scan[256] = c;
    }
    __syncthreads();
    int base = scan[t];
    if (rank >= base && rank < scan[t + 1]) {
        int c = base;
        for (int j = 0; j < 256; j++) {
            int hv = h[j];
            if (rank < c + hv) { outPair[0] = t * 256 + j; outPair[1] = rank - c; break; }
            c += hv;
        }
    }
}

// ---------- output-centric gather conv: one wave per 16 cells, lane = cout ----------
// W slab (32x64) for the current offset held in 32 VGPRs, reused across 16 cells.
// No atomics; every output element written exactly once (coalesced).

__global__ void __launch_bounds__(256)
gather_conv_kernel(const float* __restrict__ feat, const float* __restrict__ mask,
                   const float* __restrict__ W, const int* __restrict__ sel,
                   const int* __restrict__ head, const int* __restrict__ nxt,
                   float* __restrict__ out, int numOut) {
    int gid = blockIdx.x * blockDim.x + threadIdx.x;
    int wave = gid >> 6;
    int lane = threadIdx.x & 63;
    int cellBase = wave * NC;
    if (cellBase >= numOut) return;

    unsigned thrBits = ((unsigned)sel[0] << 16) | (unsigned)sel[2];
    float thr = __uint_as_float(thrBits);

    // decode base cell; NC=16 spans 2 consecutive oy (full ox range of 8)
    int tmp = cellBase / OD2;        // ox0 == 0 (cellBase % 8 == 0)
    int oy0 = tmp % OD1;             // even, so oy0+1 <= 99
    tmp /= OD1;
    int oz = tmp % OD0;
    int bb = tmp / OD0;

    float acc[NC];
#pragma unroll
    for (int i = 0; i < NC; i++) acc[i] = 0.f;
    unsigned keepMask = 0;

#pragma unroll 1
    for (int o0 = 0; o0 < 3; o0++) {
        int iz = 2 * oz + o0 - 1;
        if (iz < 0 || iz >= ID0) continue;
#pragma unroll 1
        for (int o1 = 0; o1 < 3; o1++) {
            int iy_base = 2 * oy0 + o1 - 1;
#pragma unroll 1
            for (int o2 = 0; o2 < 3; o2++) {
                int ix_off = o2 - 1;
                // load W slab for this offset: lane = cout column, coalesced rows
                const float* wp = W + (size_t)(((o0 * 3 + o1) * 3 + o2)) * (CIN * COUT) + lane;
                float w[CIN];
#pragma unroll
                for (int k = 0; k < CIN; k++) w[k] = wp[k * COUT];

#pragma unroll
                for (int dy = 0; dy < 2; dy++) {
                    int iy = iy_base + 2 * dy;
                    if (iy < 0 || iy >= ID1) continue;
                    int vbase = ((bb * ID0 + iz) * ID1 + iy) * ID2;
#pragma unroll
                    for (int ox = 0; ox < OD2; ox++) {
                        int ix = 2 * ox + ix_off;
                        if (ix < 0 || ix >= ID2) continue;
                        int ci = dy * OD2 + ox;
                        int p = head[vbase + ix];
                        while (p >= 0) {
                            const float4* f4 = (const float4*)(feat + (size_t)p * CIN);
                            float m = mask[p];
                            float a = acc[ci];
#pragma unroll
                            for (int j = 0; j < 8; j++) {
                                float4 v = f4[j];
                                a = fmaf(v.x, w[4 * j + 0], a);
                                a = fmaf(v.y, w[4 * j + 1], a);
                                a = fmaf(v.z, w[4 * j + 2], a);
                                a = fmaf(v.w, w[4 * j + 3], a);
                            }
                            acc[ci] = a;
                            if (m >= thr) keepMask |= (1u << ci);
                            p = nxt[p];
                        }
                    }
                }
            }
        }
    }

    float* outp = out + (size_t)cellBase * COUT + lane;
#pragma unroll
    for (int ci = 0; ci < NC; ci++)
        outp[(size_t)ci * COUT] = ((keepMask >> ci) & 1u) ? acc[ci] : 0.f;
}

extern "C" void kernel_launch(void* const* d_in, const int* in_sizes, int n_in,
                              void* d_out, int out_size, void* d_ws, size_t ws_size,
                              hipStream_t stream) {
    const float* feat  = (const float*)d_in[0];   // (N, 32) f32
    const int*   coors = (const int*)d_in[1];     // (N, 4)  i32
    const float* mask  = (const float*)d_in[2];   // (N,)    f32
    const float* W     = (const float*)d_in[3];   // (3,3,3,32,64) f32

    int n = in_sizes[2];                 // N
    int numOut = out_size / COUT;        // 160000
    int rank = (int)(n * 0.5);           // int(N * PRUNING_RATIO)

    char* ws = (char*)d_ws;
    int* histHi = (int*)ws;                              // 65536 ints
    int* histLo = (int*)(ws + 65536 * 4);                // 65536 ints
    int* sel    = (int*)(ws + 2 * 65536 * 4);            // [hiBucket, rank2, loBucket, pad]
    int* head   = (int*)(ws + 2 * 65536 * 4 + 64);       // NVOX ints
    int* nxt    = (int*)(ws + 2 * 65536 * 4 + 64 + (size_t)NVOX * 4); // n ints

    hipMemsetAsync(d_ws, 0, 2 * 65536 * 4 + 64, stream);          // histograms + sel
    hipMemsetAsync(head, 0xFF, (size_t)NVOX * 4, stream);         // head = -1

    const int blk = 256;
    int gN = (n + blk - 1) / blk;
    prep_kernel<<<gN, blk, 0, stream>>>(mask, coors, n, histHi, head, nxt);
    select_kernel<<<1, 256, 0, stream>>>(histHi, nullptr, rank, sel);
    hist_lo_kernel<<<gN, blk, 0, stream>>>(mask, n, sel, histLo);
    select_kernel<<<1, 256, 0, stream>>>(histLo, sel + 1, 0, sel + 2);

    int waves = (numOut + NC - 1) / NC;                  // 10000
    long long threads = (long long)waves * 64;
    int gGather = (int)((threads + blk - 1) / blk);      // 2500
    gather_conv_kernel<<<gGather, blk, 0, stream>>>(feat, mask, W, sel,
                                                    head, nxt, (float*)d_out, numOut);
}

// Round 3
// 934.919 us; speedup vs baseline: 1.0596x; 1.0596x over previous
//
#include <hip/hip_runtime.h>

#define CIN 32
#define COUT 64
#define OD0 100
#define OD1 100
#define OD2 8
#define NUMOUT (2 * OD0 * OD1 * OD2)   // 160000
#define NTILE (NUMOUT / 16)            // 10000 tiles of 16 cells
#define NBUCK (NTILE * 32)             // 320000 buckets (tile<<5 | offId)
#define CHUNK 1024
#define NCHUNK ((NBUCK + CHUNK - 1) / CHUNK)   // 313

// ---------- tap enumeration (stride-2, pad-1, dil-1: <=2 taps per dim) ----------

template <typename F>
__device__ __forceinline__ void for_taps(int4 c, F f) {
    int bb = c.x, pz = c.y, py = c.z, px = c.w;
    int oz[2], ozo[2], nz = 0, oy[2], oyo[2], ny = 0, ox[2], oxo[2], nx = 0;
#pragma unroll
    for (int o = 0; o < 3; o++) {
        int num = pz + 1 - o;
        if (num >= 0 && !(num & 1) && (num >> 1) < OD0) { oz[nz] = num >> 1; ozo[nz] = o; nz++; }
        num = py + 1 - o;
        if (num >= 0 && !(num & 1) && (num >> 1) < OD1) { oy[ny] = num >> 1; oyo[ny] = o; ny++; }
        num = px + 1 - o;
        if (num >= 0 && !(num & 1) && (num >> 1) < OD2) { ox[nx] = num >> 1; oxo[nx] = o; nx++; }
    }
    for (int a = 0; a < nz; a++)
        for (int b = 0; b < ny; b++)
            for (int d = 0; d < nx; d++) {
                int cell = ((bb * OD0 + oz[a]) * OD1 + oy[b]) * OD2 + ox[d];
                int off = (ozo[a] * 3 + oyo[b]) * 3 + oxo[d];
                f(cell, off);
            }
}

// ---------- K1: bucket counts + hi-16 mask histogram ----------

__global__ void count_kernel(const float* __restrict__ mask, const int* __restrict__ coors,
                             int n, int* __restrict__ histHi, unsigned* __restrict__ cnt) {
    int i = blockIdx.x * blockDim.x + threadIdx.x;
    if (i >= n) return;
    atomicAdd(&histHi[__float_as_uint(mask[i]) >> 16], 1);
    int4 c = ((const int4*)coors)[i];
    for_taps(c, [&](int cell, int off) {
        unsigned key = ((unsigned)(cell >> 4) << 5) | (unsigned)off;
        atomicAdd(&cnt[key], 1u);
    });
}

// ---------- K2a: per-chunk exclusive scan ----------

__global__ void __launch_bounds__(256)
scanA_kernel(const unsigned* __restrict__ cnt, unsigned* __restrict__ base,
             unsigned* __restrict__ chunkSum) {
    __shared__ unsigned s[256];
    int b = blockIdx.x, t = threadIdx.x;
    int i0 = b * CHUNK + t * 4;
    uint4 v = make_uint4(0, 0, 0, 0);
    if (i0 + 3 < NBUCK) v = *(const uint4*)(cnt + i0);
    else {
        if (i0 + 0 < NBUCK) v.x = cnt[i0 + 0];
        if (i0 + 1 < NBUCK) v.y = cnt[i0 + 1];
        if (i0 + 2 < NBUCK) v.z = cnt[i0 + 2];
        if (i0 + 3 < NBUCK) v.w = cnt[i0 + 3];
    }
    unsigned tsum = v.x + v.y + v.z + v.w;
    s[t] = tsum;
    __syncthreads();
    for (int d = 1; d < 256; d <<= 1) {
        unsigned a = (t >= d) ? s[t - d] : 0u;
        __syncthreads();
        s[t] += a;
        __syncthreads();
    }
    unsigned excl = s[t] - tsum;
    if (t == 255) chunkSum[b] = s[255];
    if (i0 + 0 < NBUCK) base[i0 + 0] = excl;
    if (i0 + 1 < NBUCK) base[i0 + 1] = excl + v.x;
    if (i0 + 2 < NBUCK) base[i0 + 2] = excl + v.x + v.y;
    if (i0 + 3 < NBUCK) base[i0 + 3] = excl + v.x + v.y + v.z;
}

// ---------- K2b: scan chunk sums + sentinel + level-1 radix select ----------

__global__ void __launch_bounds__(512)
scanB_kernel(const unsigned* __restrict__ chunkSum, unsigned* __restrict__ chunkBase,
             unsigned* __restrict__ base, const int* __restrict__ histHi,
             int rank, int* __restrict__ sel) {
    __shared__ unsigned cs[NCHUNK + 1];
    __shared__ int partial[256];
    __shared__ int scan2[257];
    int t = threadIdx.x;
    for (int i = t; i < NCHUNK; i += 512) cs[i + 1] = chunkSum[i];
    if (t == 0) cs[0] = 0;
    __syncthreads();
    if (t == 0) {
        for (int i = 1; i <= NCHUNK; i++) cs[i] += cs[i - 1];
        base[NBUCK] = cs[NCHUNK];     // sentinel: total pair count
    }
    __syncthreads();
    for (int i = t; i < NCHUNK; i += 512) chunkBase[i] = cs[i];
    // level-1 select on histHi
    if (t < 256) {
        const int* h = histHi + t * 256;
        int sum = 0;
        for (int j = 0; j < 256; j++) sum += h[j];
        partial[t] = sum;
    }
    __syncthreads();
    if (t == 0) {
        int c = 0;
        for (int j = 0; j < 256; j++) { scan2[j] = c; c += partial[j]; }
        scan2[256] = c;
    }
    __syncthreads();
    if (t < 256) {
        int bse = scan2[t];
        if (rank >= bse && rank < scan2[t + 1]) {
            int c = bse;
            const int* h = histHi + t * 256;
            for (int j = 0; j < 256; j++) {
                int hv = h[j];
                if (rank < c + hv) { sel[0] = t * 256 + j; sel[1] = rank - c; break; }
                c += hv;
            }
        }
    }
}

// ---------- K2c: add-back + cursor init ----------

__global__ void __launch_bounds__(256)
scanC_kernel(unsigned* __restrict__ base, unsigned* __restrict__ cursor,
             const unsigned* __restrict__ chunkBase) {
    int i = blockIdx.x * 256 + threadIdx.x;
    if (i >= NBUCK) return;
    unsigned v = base[i] + chunkBase[i >> 10];
    base[i] = v;
    cursor[i] = v;
}

// ---------- K3: fill pair list + lo-16 histogram ----------

__global__ void fill_kernel(const float* __restrict__ mask, const int* __restrict__ coors,
                            int n, const int* __restrict__ sel, int* __restrict__ histLo,
                            unsigned* __restrict__ cursor, unsigned* __restrict__ pairs) {
    int i = blockIdx.x * blockDim.x + threadIdx.x;
    if (i >= n) return;
    unsigned bits = __float_as_uint(mask[i]);
    if ((int)(bits >> 16) == sel[0]) atomicAdd(&histLo[bits & 0xFFFFu], 1);
    int4 c = ((const int4*)coors)[i];
    for_taps(c, [&](int cell, int off) {
        unsigned key = ((unsigned)(cell >> 4) << 5) | (unsigned)off;
        unsigned pos = atomicAdd(&cursor[key], 1u);
        pairs[pos] = ((unsigned)i << 9) | ((unsigned)off << 4) | (unsigned)(cell & 15);
    });
}

// ---------- K4: level-2 radix select ----------

__global__ void select_kernel(const int* __restrict__ hist, const int* rankSrc, int* outPair) {
    __shared__ int partial[256];
    __shared__ int scan[257];
    int t = threadIdx.x;
    int rank = *rankSrc;
    const int* h = hist + t * 256;
    int sum = 0;
    for (int j = 0; j < 256; j++) sum += h[j];
    partial[t] = sum;
    __syncthreads();
    if (t == 0) {
        int c = 0;
        for (int j = 0; j < 256; j++) { scan[j] = c; c += partial[j]; }
        scan[256] = c;
    }
    __syncthreads();
    int bse = scan[t];
    if (rank >= bse && rank < scan[t + 1]) {
        int c = bse;
        for (int j = 0; j < 256; j++) {
            int hv = h[j];
            if (rank < c + hv) { outPair[0] = t * 256 + j; outPair[1] = rank - c; break; }
            c += hv;
        }
    }
}

// ---------- K5: flat rulebook gather, one wave per 16-cell tile ----------
// Pairs for a tile are contiguous and sorted by offId; W slab (32x64) kept in
// 32 VGPRs, reloaded only on offId change. Feature loads A/B double-buffered.
// Accumulators in LDS (acc[ci][lane], 2-way bank alias = free). No atomics.

#define LOADF(buf, e, m)                                                      \
    {                                                                         \
        unsigned p_ = (e) >> 9;                                               \
        const float4* fp_ = (const float4*)(feat + ((size_t)p_ << 5));        \
        _Pragma("unroll") for (int q = 0; q < 8; q++) buf[q] = fp_[q];        \
        m = mask[p_];                                                         \
    }

#define PROC(e, F, m)                                                         \
    {                                                                         \
        int off_ = ((e) >> 4) & 31;                                           \
        int ci_ = (e) & 15;                                                   \
        if (off_ != curOff) {                                                 \
            curOff = off_;                                                    \
            const float* wp_ = Wg + ((size_t)off_ << 11) + lane;              \
            _Pragma("unroll") for (int k = 0; k < 32; k++) w[k] = wp_[k << 6];\
        }                                                                     \
        float s_ = 0.f;                                                       \
        _Pragma("unroll") for (int q = 0; q < 8; q++) {                       \
            s_ = fmaf(F[q].x, w[4 * q + 0], s_);                              \
            s_ = fmaf(F[q].y, w[4 * q + 1], s_);                              \
            s_ = fmaf(F[q].z, w[4 * q + 2], s_);                              \
            s_ = fmaf(F[q].w, w[4 * q + 3], s_);                              \
        }                                                                     \
        acc[(ci_ << 6) | lane] += s_;                                         \
        if ((m) >= thr) keepM |= (1u << ci_);                                 \
    }

__global__ void __launch_bounds__(256, 4)
gather_kernel(const float* __restrict__ feat, const float* __restrict__ mask,
              const float* __restrict__ Wg, const int* __restrict__ sel,
              const unsigned* __restrict__ bucketBase, const unsigned* __restrict__ pairs,
              float* __restrict__ out) {
    __shared__ float accS[4][16 * 64];
    int t = threadIdx.x, wv = t >> 6, lane = t & 63;
    float* acc = accS[wv];
    int tile = blockIdx.x * 4 + wv;
#pragma unroll
    for (int q = 0; q < 16; q++) acc[(q << 6) | lane] = 0.f;

    unsigned thrBits = (((unsigned)sel[0]) << 16) | (unsigned)sel[2];
    float thr = __uint_as_float(thrBits);

    unsigned i = bucketBase[(unsigned)tile << 5];
    unsigned end = bucketBase[(unsigned)(tile + 1) << 5];
    unsigned cnt = end - i;

    float w[32];
    int curOff = -1;
    unsigned keepM = 0;
    float4 A[8], B[8];
    unsigned eA = 0, eB = 0;
    float mA = 0.f, mB = 0.f;

    if (cnt) { eA = pairs[i]; LOADF(A, eA, mA); }
    while (cnt >= 2) {
        eB = pairs[i + 1];
        LOADF(B, eB, mB);
        PROC(eA, A, mA);
        if (cnt >= 3) { eA = pairs[i + 2]; LOADF(A, eA, mA); }
        PROC(eB, B, mB);
        i += 2;
        cnt -= 2;
    }
    if (cnt == 1) PROC(eA, A, mA);

    float* outp = out + ((size_t)tile << 10) + lane;
#pragma unroll
    for (int ci = 0; ci < 16; ci++)
        outp[(size_t)ci << 6] = ((keepM >> ci) & 1u) ? acc[(ci << 6) | lane] : 0.f;
}

// ---------- host ----------

extern "C" void kernel_launch(void* const* d_in, const int* in_sizes, int n_in,
                              void* d_out, int out_size, void* d_ws, size_t ws_size,
                              hipStream_t stream) {
    const float* feat  = (const float*)d_in[0];   // (N, 32) f32
    const int*   coors = (const int*)d_in[1];     // (N, 4)  i32
    const float* mask  = (const float*)d_in[2];   // (N,)    f32
    const float* W     = (const float*)d_in[3];   // (3,3,3,32,64) f32

    int n = in_sizes[2];
    int rank = (int)(n * 0.5);

    char* ws = (char*)d_ws;
    size_t o = 0;
    int* histHi = (int*)(ws + o);            o += 65536 * 4;          // 256 KB
    int* histLo = (int*)(ws + o);            o += 65536 * 4;          // 256 KB
    int* sel    = (int*)(ws + o);            o += 256;                // 4 ints + pad
    unsigned* cnt = (unsigned*)(ws + o);     o += (size_t)NBUCK * 4;  // 1.25 MB
    size_t memsetBytes = o;                  // hist+sel+cnt all zeroed in one shot
    unsigned* base = (unsigned*)(ws + o);    o += ((size_t)NBUCK + 4) * 4;
    unsigned* cursor = (unsigned*)(ws + o);  o += (size_t)NBUCK * 4;
    unsigned* chunkSum = (unsigned*)(ws + o); o += ((size_t)NCHUNK + 3) * 4;
    unsigned* chunkBase = (unsigned*)(ws + o); o += ((size_t)NCHUNK + 3) * 4;
    o = (o + 15) & ~(size_t)15;
    unsigned* pairs = (unsigned*)(ws + o);   // up to N*8 * 4B = 12.8 MB

    hipMemsetAsync(d_ws, 0, memsetBytes, stream);

    const int blk = 256;
    int gN = (n + blk - 1) / blk;
    count_kernel<<<gN, blk, 0, stream>>>(mask, coors, n, histHi, cnt);
    scanA_kernel<<<NCHUNK, 256, 0, stream>>>(cnt, base, chunkSum);
    scanB_kernel<<<1, 512, 0, stream>>>(chunkSum, chunkBase, base, histHi, rank, sel);
    scanC_kernel<<<NBUCK / 256, 256, 0, stream>>>(base, cursor, chunkBase);
    fill_kernel<<<gN, blk, 0, stream>>>(mask, coors, n, sel, histLo, cursor, pairs);
    select_kernel<<<1, 256, 0, stream>>>(histLo, sel + 1, sel + 2);
    gather_kernel<<<NTILE / 4, 256, 0, stream>>>(feat, mask, W, sel, base, pairs,
                                                 (float*)d_out);
}

// Round 4
// 893.956 us; speedup vs baseline: 1.1081x; 1.0458x over previous
//
#include <hip/hip_runtime.h>

#define CIN 32
#define COUT 64
#define OD0 100
#define OD1 100
#define OD2 8
#define NUMOUT (2 * OD0 * OD1 * OD2)   // 160000
#define NTILE (NUMOUT / 16)            // 10000 tiles of 16 cells
#define NBUCK (NTILE * 32)             // 320000 buckets (tile<<5 | offId)
#define CHUNK 1024
#define NCHUNK ((NBUCK + CHUNK - 1) / CHUNK)   // 313
#define NWPK (27 * 64 * 32)            // prepacked W: bf16 elements

typedef short short8 __attribute__((ext_vector_type(8)));
typedef float f32x4 __attribute__((ext_vector_type(4)));

__device__ __forceinline__ unsigned short f2bf(float f) {
    unsigned u = __float_as_uint(f);
    u += 0x7FFFu + ((u >> 16) & 1u);      // RNE
    return (unsigned short)(u >> 16);
}

// ---------- tap enumeration (stride-2, pad-1, dil-1: <=2 taps per dim) ----------

template <typename F>
__device__ __forceinline__ void for_taps(int4 c, F f) {
    int bb = c.x, pz = c.y, py = c.z, px = c.w;
    int oz[2], ozo[2], nz = 0, oy[2], oyo[2], ny = 0, ox[2], oxo[2], nx = 0;
#pragma unroll
    for (int o = 0; o < 3; o++) {
        int num = pz + 1 - o;
        if (num >= 0 && !(num & 1) && (num >> 1) < OD0) { oz[nz] = num >> 1; ozo[nz] = o; nz++; }
        num = py + 1 - o;
        if (num >= 0 && !(num & 1) && (num >> 1) < OD1) { oy[ny] = num >> 1; oyo[ny] = o; ny++; }
        num = px + 1 - o;
        if (num >= 0 && !(num & 1) && (num >> 1) < OD2) { ox[nx] = num >> 1; oxo[nx] = o; nx++; }
    }
    for (int a = 0; a < nz; a++)
        for (int b = 0; b < ny; b++)
            for (int d = 0; d < nx; d++) {
                int cell = ((bb * OD0 + oz[a]) * OD1 + oy[b]) * OD2 + ox[d];
                int off = (ozo[a] * 3 + oyo[b]) * 3 + oxo[d];
                f(cell, off);
            }
}

// ---------- K0: prepack W to bf16 in MFMA B-fragment order ----------
// layout: wpk[((off*64 + lane)*4 + b)*8 + j] = bf16( W[off][k][cout] )
//   with k = (lane>>4)*8 + j, cout = b*16 + (lane&15)

__global__ void prepack_kernel(const float* __restrict__ W, unsigned short* __restrict__ wpk) {
    int idx = blockIdx.x * 256 + threadIdx.x;
    if (idx >= NWPK) return;
    int j = idx & 7, b = (idx >> 3) & 3, lane = (idx >> 5) & 63, off = idx >> 11;
    int k = ((lane >> 4) << 3) + j;
    int cout = (b << 4) + (lane & 15);
    wpk[idx] = f2bf(W[off * (CIN * COUT) + k * COUT + cout]);
}

// ---------- K1: bucket counts + hi-16 mask histogram ----------

__global__ void count_kernel(const float* __restrict__ mask, const int* __restrict__ coors,
                             int n, int* __restrict__ histHi, unsigned* __restrict__ cnt) {
    int i = blockIdx.x * blockDim.x + threadIdx.x;
    if (i >= n) return;
    atomicAdd(&histHi[__float_as_uint(mask[i]) >> 16], 1);
    int4 c = ((const int4*)coors)[i];
    for_taps(c, [&](int cell, int off) {
        unsigned key = ((unsigned)(cell >> 4) << 5) | (unsigned)off;
        atomicAdd(&cnt[key], 1u);
    });
}

// ---------- K2a: per-chunk exclusive scan ----------

__global__ void __launch_bounds__(256)
scanA_kernel(const unsigned* __restrict__ cnt, unsigned* __restrict__ base,
             unsigned* __restrict__ chunkSum) {
    __shared__ unsigned s[256];
    int b = blockIdx.x, t = threadIdx.x;
    int i0 = b * CHUNK + t * 4;
    uint4 v = make_uint4(0, 0, 0, 0);
    if (i0 + 3 < NBUCK) v = *(const uint4*)(cnt + i0);
    else {
        if (i0 + 0 < NBUCK) v.x = cnt[i0 + 0];
        if (i0 + 1 < NBUCK) v.y = cnt[i0 + 1];
        if (i0 + 2 < NBUCK) v.z = cnt[i0 + 2];
        if (i0 + 3 < NBUCK) v.w = cnt[i0 + 3];
    }
    unsigned tsum = v.x + v.y + v.z + v.w;
    s[t] = tsum;
    __syncthreads();
    for (int d = 1; d < 256; d <<= 1) {
        unsigned a = (t >= d) ? s[t - d] : 0u;
        __syncthreads();
        s[t] += a;
        __syncthreads();
    }
    unsigned excl = s[t] - tsum;
    if (t == 255) chunkSum[b] = s[255];
    if (i0 + 0 < NBUCK) base[i0 + 0] = excl;
    if (i0 + 1 < NBUCK) base[i0 + 1] = excl + v.x;
    if (i0 + 2 < NBUCK) base[i0 + 2] = excl + v.x + v.y;
    if (i0 + 3 < NBUCK) base[i0 + 3] = excl + v.x + v.y + v.z;
}

// ---------- parallel two-level radix select (needs >=256 threads at barriers) ----------

__device__ void selectDev(const int* __restrict__ hist, int rank, int* __restrict__ out) {
    __shared__ int p1[256];
    __shared__ int sc[256];
    __shared__ int wT, wB;
    int t = threadIdx.x;
    int mySum = 0;
    if (t < 256) {
        const int* h = hist + t * 256;
        for (int j = 0; j < 256; j++) mySum += h[j];
        sc[t] = mySum;
        p1[t] = mySum;
    }
    __syncthreads();
    for (int d = 1; d < 256; d <<= 1) {
        int a = 0;
        if (t < 256 && t >= d) a = sc[t - d];
        __syncthreads();
        if (t < 256) sc[t] += a;
        __syncthreads();
    }
    if (t < 256) {
        int excl = sc[t] - p1[t];
        if (rank >= excl && rank < sc[t]) { wT = t; wB = excl; }
    }
    __syncthreads();
    int hiT = wT, r2 = rank - wB;
    int hv = 0;
    if (t < 256) {
        hv = hist[hiT * 256 + t];
        sc[t] = hv;
    }
    __syncthreads();
    for (int d = 1; d < 256; d <<= 1) {
        int a = 0;
        if (t < 256 && t >= d) a = sc[t - d];
        __syncthreads();
        if (t < 256) sc[t] += a;
        __syncthreads();
    }
    if (t < 256) {
        int excl = sc[t] - hv;
        if (r2 >= excl && r2 < sc[t]) { out[0] = hiT * 256 + t; out[1] = r2 - excl; }
    }
}

// ---------- K2b: chunk-sum scan + sentinel + level-1 select ----------

__global__ void __launch_bounds__(512)
scanB_kernel(const unsigned* __restrict__ chunkSum, unsigned* __restrict__ chunkBase,
             unsigned* __restrict__ base, const int* __restrict__ histHi,
             int rank, int* __restrict__ sel) {
    __shared__ unsigned cs[512];
    int t = threadIdx.x;
    unsigned v0 = (t < NCHUNK) ? chunkSum[t] : 0u;
    cs[t] = v0;
    __syncthreads();
    for (int d = 1; d < 512; d <<= 1) {
        unsigned a = (t >= d) ? cs[t - d] : 0u;
        __syncthreads();
        cs[t] += a;
        __syncthreads();
    }
    if (t < NCHUNK) chunkBase[t] = cs[t] - v0;
    if (t == 511) base[NBUCK] = cs[511];
    __syncthreads();
    selectDev(histHi, rank, sel);
}

// ---------- K2c: add-back + cursor init, fused lo-16 histogram ----------

__global__ void __launch_bounds__(256)
scanC_kernel(unsigned* __restrict__ base, unsigned* __restrict__ cursor,
             const unsigned* __restrict__ chunkBase,
             const float* __restrict__ mask, int n,
             const int* __restrict__ sel, int* __restrict__ histLo) {
    int i = blockIdx.x * 256 + threadIdx.x;
    if (i < NBUCK) {
        unsigned v = base[i] + chunkBase[i >> 10];
        base[i] = v;
        cursor[i] = v;
    }
    if (i < n) {
        unsigned bits = __float_as_uint(mask[i]);
        if ((int)(bits >> 16) == sel[0]) atomicAdd(&histLo[bits & 0xFFFFu], 1);
    }
}

// ---------- K2d: level-2 select ----------

__global__ void __launch_bounds__(256)
select2_kernel(const int* __restrict__ histLo, const int* __restrict__ sel, int* __restrict__ out) {
    selectDev(histLo, sel[1], out);
}

// ---------- K3: fill pair list + keep bitmap (thr known) ----------

__global__ void fillkeep_kernel(const float* __restrict__ mask, const int* __restrict__ coors,
                                int n, const int* __restrict__ sel,
                                unsigned* __restrict__ cursor, unsigned* __restrict__ pairs,
                                unsigned char* __restrict__ keepB) {
    int i = blockIdx.x * blockDim.x + threadIdx.x;
    if (i >= n) return;
    unsigned thrBits = (((unsigned)sel[0]) << 16) | (unsigned)sel[2];
    float thr = __uint_as_float(thrBits);
    bool imp = mask[i] >= thr;
    int4 c = ((const int4*)coors)[i];
    for_taps(c, [&](int cell, int off) {
        unsigned key = ((unsigned)(cell >> 4) << 5) | (unsigned)off;
        unsigned pos = atomicAdd(&cursor[key], 1u);
        pairs[pos] = ((unsigned)i << 4) | (unsigned)(cell & 15);
        if (imp) keepB[cell] = 1;
    });
}

// ---------- K4: MFMA gather. one wave per 16-cell tile; 16-pair batches ----------
// A(16x32) = batch features (bf16), B(32x64) = W[off] prepacked. Lane L loads
// row L&15's k-range (L>>4)*8..+7 (2 dwordx4/wave vs 128 broadcast loads).
// C rows are independent -> padded rows computed but not scattered.

__global__ void __launch_bounds__(256, 4)
gather_kernel(const float* __restrict__ feat, const unsigned short* __restrict__ wpk,
              const unsigned char* __restrict__ keepB,
              const unsigned* __restrict__ bucketBase, const unsigned* __restrict__ pairs,
              float* __restrict__ out) {
    __shared__ float accS[4][16 * 64];
    int t = threadIdx.x, wv = t >> 6, lane = t & 63;
    int l16 = lane & 15, quad = lane >> 4;
    float* acc = accS[wv];
    int tile = blockIdx.x * 4 + wv;

    // zero wave-private accumulator (no barriers needed anywhere)
    float4* accv = (float4*)acc;
#pragma unroll
    for (int q = 0; q < 4; q++) accv[q * 64 + lane] = make_float4(0.f, 0.f, 0.f, 0.f);

    unsigned char kb = keepB[tile * 16 + l16];
    unsigned keepM = (unsigned)(__ballot(kb != 0) & 0xFFFFull);

    unsigned i = bucketBase[(unsigned)tile << 5];
    unsigned lastIdx = bucketBase[NBUCK];       // sentinel: total pair count

#pragma unroll 1
    for (int off = 0; off < 27; off++) {
        unsigned end = bucketBase[((unsigned)tile << 5) + off + 1];
        if (i >= end) continue;
        const unsigned short* wb = wpk + ((size_t)(off * 64 + lane)) * 32;
        short8 B0 = *(const short8*)(wb + 0);
        short8 B1 = *(const short8*)(wb + 8);
        short8 B2 = *(const short8*)(wb + 16);
        short8 B3 = *(const short8*)(wb + 24);
        do {
            unsigned c = end - i;
            if (c > 16u) c = 16u;
            unsigned idx = i + (unsigned)l16;
            if (idx >= lastIdx) idx = lastIdx - 1;
            unsigned e = pairs[idx];
            if ((unsigned)l16 >= c) e = 0xFFFFFFFFu;

            // A fragment: my row = l16, k = quad*8 + j
            unsigned p = (e != 0xFFFFFFFFu) ? (e >> 4) : 0u;
            const float4* fp = (const float4*)(feat + ((size_t)p << 5) + (quad << 3));
            float4 fa = fp[0], fb = fp[1];
            short8 A;
            A[0] = (short)f2bf(fa.x); A[1] = (short)f2bf(fa.y);
            A[2] = (short)f2bf(fa.z); A[3] = (short)f2bf(fa.w);
            A[4] = (short)f2bf(fb.x); A[5] = (short)f2bf(fb.y);
            A[6] = (short)f2bf(fb.z); A[7] = (short)f2bf(fb.w);

            f32x4 z = {0.f, 0.f, 0.f, 0.f};
            f32x4 c0 = __builtin_amdgcn_mfma_f32_16x16x32_bf16(A, B0, z, 0, 0, 0);
            f32x4 c1 = __builtin_amdgcn_mfma_f32_16x16x32_bf16(A, B1, z, 0, 0, 0);
            f32x4 c2 = __builtin_amdgcn_mfma_f32_16x16x32_bf16(A, B2, z, 0, 0, 0);
            f32x4 c3 = __builtin_amdgcn_mfma_f32_16x16x32_bf16(A, B3, z, 0, 0, 0);

            // scatter: my C rows are quad*4+r, col = l16
#pragma unroll
            for (int r = 0; r < 4; r++) {
                unsigned es = __shfl(e, quad * 4 + r);
                if (es != 0xFFFFFFFFu) {
                    float* ap = acc + ((es & 15u) << 6) + l16;
                    atomicAdd(ap + 0,  c0[r]);
                    atomicAdd(ap + 16, c1[r]);
                    atomicAdd(ap + 32, c2[r]);
                    atomicAdd(ap + 48, c3[r]);
                }
            }
            i += c;
        } while (i < end);
    }

    float* outp = out + ((size_t)tile << 10);
#pragma unroll
    for (int ci = 0; ci < 16; ci++) {
        float v = acc[(ci << 6) + lane];
        outp[(ci << 6) + lane] = ((keepM >> ci) & 1u) ? v : 0.f;
    }
}

// ---------- host ----------

extern "C" void kernel_launch(void* const* d_in, const int* in_sizes, int n_in,
                              void* d_out, int out_size, void* d_ws, size_t ws_size,
                              hipStream_t stream) {
    const float* feat  = (const float*)d_in[0];   // (N, 32) f32
    const int*   coors = (const int*)d_in[1];     // (N, 4)  i32
    const float* mask  = (const float*)d_in[2];   // (N,)    f32
    const float* W     = (const float*)d_in[3];   // (3,3,3,32,64) f32

    int n = in_sizes[2];
    int rank = (int)(n * 0.5);

    char* ws = (char*)d_ws;
    size_t o = 0;
    int* histHi = (int*)(ws + o);             o += 65536 * 4;
    int* histLo = (int*)(ws + o);             o += 65536 * 4;
    int* sel    = (int*)(ws + o);             o += 256;
    unsigned* cnt = (unsigned*)(ws + o);      o += (size_t)NBUCK * 4;
    unsigned char* keepB = (unsigned char*)(ws + o); o += (NUMOUT + 64);
    size_t memsetBytes = o;                   // everything above zeroed in one shot
    o = (o + 15) & ~(size_t)15;
    unsigned* base = (unsigned*)(ws + o);     o += ((size_t)NBUCK + 4) * 4;
    unsigned* cursor = (unsigned*)(ws + o);   o += (size_t)NBUCK * 4;
    unsigned* chunkSum = (unsigned*)(ws + o); o += 512 * 4;
    unsigned* chunkBase = (unsigned*)(ws + o); o += 512 * 4;
    unsigned short* wpk = (unsigned short*)(ws + o); o += (size_t)NWPK * 2;
    o = (o + 15) & ~(size_t)15;
    unsigned* pairs = (unsigned*)(ws + o);    // up to N*8*4 B = 12.8 MB (+slack)

    hipMemsetAsync(d_ws, 0, memsetBytes, stream);

    const int blk = 256;
    int gN = (n + blk - 1) / blk;
    prepack_kernel<<<(NWPK + 255) / 256, 256, 0, stream>>>(W, wpk);
    count_kernel<<<gN, blk, 0, stream>>>(mask, coors, n, histHi, cnt);
    scanA_kernel<<<NCHUNK, 256, 0, stream>>>(cnt, base, chunkSum);
    scanB_kernel<<<1, 512, 0, stream>>>(chunkSum, chunkBase, base, histHi, rank, sel);
    scanC_kernel<<<gN, 256, 0, stream>>>(base, cursor, chunkBase, mask, n, sel, histLo);
    select2_kernel<<<1, 256, 0, stream>>>(histLo, sel, sel + 2);
    fillkeep_kernel<<<gN, blk, 0, stream>>>(mask, coors, n, sel, cursor, pairs, keepB);
    gather_kernel<<<NTILE / 4, 256, 0, stream>>>(feat, wpk, keepB, base, pairs,
                                                 (float*)d_out);
}